// Round 3
// baseline (1425.093 us; speedup 1.0000x reference)
//
#include <hip/hip_runtime.h>
#include <math.h>

typedef __attribute__((ext_vector_type(4))) float f32x4;
typedef __attribute__((ext_vector_type(8))) short bf16x8;

#define DI __device__ __forceinline__

DI unsigned short f32_to_bf16(float f) {
  unsigned int u = __float_as_uint(f);
  u += 0x7FFFu + ((u >> 16) & 1u);   // round-to-nearest-even
  return (unsigned short)(u >> 16);
}

static constexpr float kCode[16] = {
    -1.0f, -0.6961928009986877f, -0.5250730514526367f, -0.39491748809814453f,
    -0.28444138169288635f, -0.18477343022823334f, -0.09105003625154495f, 0.0f,
    0.07958029955625534f, 0.16093020141124725f, 0.24611230194568634f,
    0.33791524171829224f, 0.44070982933044434f, 0.5626170039176941f,
    0.7229568362236023f, 1.0f};

// ---------------------------------------------------------------------------
// NF4 quant-dequant (block=64): 16 lanes/block, float4/lane.
// ---------------------------------------------------------------------------
__global__ void __launch_bounds__(256) k_dequant_nf4(
    const float* __restrict__ in, unsigned short* __restrict__ out, int n4) {
  int i = blockIdx.x * 256 + threadIdx.x;
  if (i >= n4) return;
  f32x4 v = reinterpret_cast<const f32x4*>(in)[i];
  float am = fmaxf(fmaxf(fabsf(v.x), fabsf(v.y)), fmaxf(fabsf(v.z), fabsf(v.w)));
  am = fmaxf(am, __shfl_xor(am, 1));
  am = fmaxf(am, __shfl_xor(am, 2));
  am = fmaxf(am, __shfl_xor(am, 4));
  am = fmaxf(am, __shfl_xor(am, 8));
  float scale = (am == 0.0f) ? 1.0f : am;
  unsigned short o[4];
#pragma unroll
  for (int j = 0; j < 4; ++j) {
    float nv = ((const float*)&v)[j] / scale;
    int idx = 0;
#pragma unroll
    for (int b = 0; b < 15; ++b)
      idx += (nv > 0.5f * (kCode[b] + kCode[b + 1])) ? 1 : 0;
    o[j] = f32_to_bf16(kCode[idx] * am);
  }
  reinterpret_cast<ushort4*>(out)[i] = make_ushort4(o[0], o[1], o[2], o[3]);
}

__global__ void __launch_bounds__(256) k_f32_to_bf16(
    const float* __restrict__ in, unsigned short* __restrict__ out, int n4) {
  int i = blockIdx.x * 256 + threadIdx.x;
  if (i >= n4) return;
  f32x4 v = reinterpret_cast<const f32x4*>(in)[i];
  reinterpret_cast<ushort4*>(out)[i] =
      make_ushort4(f32_to_bf16(v.x), f32_to_bf16(v.y), f32_to_bf16(v.z), f32_to_bf16(v.w));
}

// ---------------------------------------------------------------------------
// Pipelined GEMM helpers
// ---------------------------------------------------------------------------
DI void gload16(const void* g, void* l) {
  __builtin_amdgcn_global_load_lds(
      (const __attribute__((address_space(1))) void*)g,
      (__attribute__((address_space(3))) void*)l, 16, 0, 0);
}

DI void barrier_nodrain() {
  asm volatile("" ::: "memory");
  __builtin_amdgcn_s_barrier();
  asm volatile("" ::: "memory");
}

#define WAITV(N) asm volatile("s_waitcnt vmcnt(" #N ")" ::: "memory")
#define LGKM0 do { asm volatile("s_waitcnt lgkmcnt(0)" ::: "memory"); \
                   __builtin_amdgcn_sched_barrier(0); } while (0)

// Swizzle scheme (both GEMMs): LDS rows are 128B (BK=64 bf16). Element (r,e)
// lives at byte r*128 + (2e ^ ((r&7)<<4)). global_load_lds writes linearly;
// the global source column is pre-inverse-swizzled per lane:
//   lane l of chunk c: row = c*8 + (l>>3), col = ((l&7)^(l>>3))*8.

// ---------------------------------------------------------------------------
// Fused dual GEMM + SwiGLU. BM=256, BN=128 (per B), BK=64, 8 waves (4M x 2N),
// per-wave 64x64 per B. 4 phase-locked phases/tile, vmcnt(6) per tile.
// LDS: A 32K x2buf | B1 16K x2 | B2 16K x2 = 128 KiB.
// ---------------------------------------------------------------------------
__global__ void __launch_bounds__(512, 2) k_gemm_dual_swiglu(
    const unsigned short* __restrict__ X,
    const unsigned short* __restrict__ W1,
    const unsigned short* __restrict__ W2,
    unsigned short* __restrict__ H) {
  constexpr int K = 4096, N = 11008, NK = K / 64;
  __shared__ char ldsb[131072];

  const int tid = threadIdx.x;
  const int w = tid >> 6, l = tid & 63;

  const int bid = blockIdx.x;               // 1376 = 8 * 172
  const int lt = (bid & 7) * 172 + (bid >> 3);
  const int mt = lt & 15, nt = lt >> 4;
  const int m0 = mt * 256, n0 = nt * 128;

  const int wr = w >> 1, wc = w & 1;

  // staging sources (pre-inverse-swizzled)
  const int lr = l >> 3;
  const int lc = ((l & 7) ^ lr) * 8;
  const unsigned short* sA0  = X  + (size_t)(m0 + (w * 4 + 0) * 8 + lr) * K + lc;
  const unsigned short* sA1  = X  + (size_t)(m0 + (w * 4 + 1) * 8 + lr) * K + lc;
  const unsigned short* sA2  = X  + (size_t)(m0 + (w * 4 + 2) * 8 + lr) * K + lc;
  const unsigned short* sA3  = X  + (size_t)(m0 + (w * 4 + 3) * 8 + lr) * K + lc;
  const unsigned short* sB10 = W1 + (size_t)(n0 + (w * 2 + 0) * 8 + lr) * K + lc;
  const unsigned short* sB11 = W1 + (size_t)(n0 + (w * 2 + 1) * 8 + lr) * K + lc;
  const unsigned short* sB20 = W2 + (size_t)(n0 + (w * 2 + 0) * 8 + lr) * K + lc;
  const unsigned short* sB21 = W2 + (size_t)(n0 + (w * 2 + 1) * 8 + lr) * K + lc;

#define ST_A_LO(t, BUF) { gload16(sA0 + (size_t)(t) * 64, ldsb + (BUF) * 32768 + (w * 4 + 0) * 1024); \
                          gload16(sA1 + (size_t)(t) * 64, ldsb + (BUF) * 32768 + (w * 4 + 1) * 1024); }
#define ST_A_HI(t, BUF) { gload16(sA2 + (size_t)(t) * 64, ldsb + (BUF) * 32768 + (w * 4 + 2) * 1024); \
                          gload16(sA3 + (size_t)(t) * 64, ldsb + (BUF) * 32768 + (w * 4 + 3) * 1024); }
#define ST_B1(t, BUF)   { gload16(sB10 + (size_t)(t) * 64, ldsb + 65536 + (BUF) * 16384 + (w * 2 + 0) * 1024); \
                          gload16(sB11 + (size_t)(t) * 64, ldsb + 65536 + (BUF) * 16384 + (w * 2 + 1) * 1024); }
#define ST_B2(t, BUF)   { gload16(sB20 + (size_t)(t) * 64, ldsb + 98304 + (BUF) * 16384 + (w * 2 + 0) * 1024); \
                          gload16(sB21 + (size_t)(t) * 64, ldsb + 98304 + (BUF) * 16384 + (w * 2 + 1) * 1024); }

  // ds_read bases (swizzled): slot(ks) = (((ks<<2)|(l>>4)) ^ (l&7)) << 4
  const int slot0 = (((l >> 4)) ^ (l & 7)) << 4;
  const int slot1 = ((4 | (l >> 4)) ^ (l & 7)) << 4;
  const char* rdA  = ldsb + (wr * 64 + (l & 15)) * 128;
  const char* rdB1 = ldsb + 65536 + (wc * 64 + (l & 15)) * 128;
  const char* rdB2 = ldsb + 98304 + (wc * 64 + (l & 15)) * 128;

  f32x4 acc1[4][4] = {};
  f32x4 acc2[4][4] = {};
  bf16x8 a[4][2], b1[4], b2[4];

  // prologue: tile0 full + A(1),B1(1); keep 6 in flight
  ST_A_LO(0, 0); ST_A_HI(0, 0); ST_B1(0, 0); ST_B2(0, 0);
  ST_A_LO(1, 1); ST_A_HI(1, 1); ST_B1(1, 1);
  WAITV(6);
  barrier_nodrain();

#define DUAL_TILE(T, BUF) { \
  const char* A_  = rdA  + (BUF) * 32768; \
  const char* B1_ = rdB1 + (BUF) * 16384; \
  const char* B2_ = rdB2 + (BUF) * 16384; \
  /* ph1: read all a + b1 ks0; stage B2(T+1); MFMA acc1 ks0 */ \
  _Pragma("unroll") for (int m = 0; m < 4; ++m) { \
    a[m][0] = *(const bf16x8*)(A_ + m * 2048 + slot0); \
    a[m][1] = *(const bf16x8*)(A_ + m * 2048 + slot1); } \
  _Pragma("unroll") for (int n = 0; n < 4; ++n) \
    b1[n] = *(const bf16x8*)(B1_ + n * 2048 + slot0); \
  if ((T) + 1 < NK) ST_B2((T) + 1, (BUF) ^ 1); \
  barrier_nodrain(); LGKM0; \
  __builtin_amdgcn_s_setprio(1); \
  _Pragma("unroll") for (int m = 0; m < 4; ++m) \
    _Pragma("unroll") for (int n = 0; n < 4; ++n) \
      acc1[m][n] = __builtin_amdgcn_mfma_f32_16x16x32_bf16(a[m][0], b1[n], acc1[m][n], 0, 0, 0); \
  __builtin_amdgcn_s_setprio(0); \
  barrier_nodrain(); \
  /* ph2: read b1 ks1; stage A(T+2) lo; MFMA acc1 ks1 */ \
  _Pragma("unroll") for (int n = 0; n < 4; ++n) \
    b1[n] = *(const bf16x8*)(B1_ + n * 2048 + slot1); \
  if ((T) + 2 < NK) ST_A_LO((T) + 2, BUF); \
  barrier_nodrain(); LGKM0; \
  __builtin_amdgcn_s_setprio(1); \
  _Pragma("unroll") for (int m = 0; m < 4; ++m) \
    _Pragma("unroll") for (int n = 0; n < 4; ++n) \
      acc1[m][n] = __builtin_amdgcn_mfma_f32_16x16x32_bf16(a[m][1], b1[n], acc1[m][n], 0, 0, 0); \
  __builtin_amdgcn_s_setprio(0); \
  barrier_nodrain(); \
  /* ph3: read b2 ks0; stage A(T+2) hi; MFMA acc2 ks0 */ \
  _Pragma("unroll") for (int n = 0; n < 4; ++n) \
    b2[n] = *(const bf16x8*)(B2_ + n * 2048 + slot0); \
  if ((T) + 2 < NK) ST_A_HI((T) + 2, BUF); \
  barrier_nodrain(); LGKM0; \
  __builtin_amdgcn_s_setprio(1); \
  _Pragma("unroll") for (int m = 0; m < 4; ++m) \
    _Pragma("unroll") for (int n = 0; n < 4; ++n) \
      acc2[m][n] = __builtin_amdgcn_mfma_f32_16x16x32_bf16(a[m][0], b2[n], acc2[m][n], 0, 0, 0); \
  __builtin_amdgcn_s_setprio(0); \
  barrier_nodrain(); \
  /* ph4: read b2 ks1; stage B1(T+2); MFMA acc2 ks1; boundary wait */ \
  _Pragma("unroll") for (int n = 0; n < 4; ++n) \
    b2[n] = *(const bf16x8*)(B2_ + n * 2048 + slot1); \
  if ((T) + 2 < NK) ST_B1((T) + 2, BUF); \
  barrier_nodrain(); LGKM0; \
  __builtin_amdgcn_s_setprio(1); \
  _Pragma("unroll") for (int m = 0; m < 4; ++m) \
    _Pragma("unroll") for (int n = 0; n < 4; ++n) \
      acc2[m][n] = __builtin_amdgcn_mfma_f32_16x16x32_bf16(a[m][1], b2[n], acc2[m][n], 0, 0, 0); \
  __builtin_amdgcn_s_setprio(0); \
  if ((T) + 2 < NK) { WAITV(6); } else if ((T) + 1 < NK) { WAITV(0); } \
  barrier_nodrain(); }

  for (int tt = 0; tt < NK; tt += 2) {
    DUAL_TILE(tt, 0);
    DUAL_TILE(tt + 1, 1);
  }
#undef DUAL_TILE
#undef ST_A_LO
#undef ST_A_HI
#undef ST_B1
#undef ST_B2

  // epilogue: silu(gate)*up -> bf16
  const int er = (l >> 4) * 4, ec = l & 15;
#pragma unroll
  for (int m = 0; m < 4; ++m)
#pragma unroll
    for (int n = 0; n < 4; ++n)
#pragma unroll
      for (int j = 0; j < 4; ++j) {
        float g = acc1[m][n][j];
        float u = acc2[m][n][j];
        float s = g / (1.0f + expf(-g));
        const int row = m0 + wr * 64 + m * 16 + er + j;
        const int col = n0 + wc * 64 + n * 16 + ec;
        H[(size_t)row * N + col] = f32_to_bf16(s * u);
      }
}

// ---------------------------------------------------------------------------
// Output GEMM. BM=BN=256, BK=64, 8 waves (2M x 4N), per-wave 128x64.
// 4 phase-locked phases/tile, vmcnt(8) per tile.
// LDS: A 32K x2 | B 32K x2 = 128 KiB.
// ---------------------------------------------------------------------------
__global__ void __launch_bounds__(512, 2) k_gemm_out(
    const unsigned short* __restrict__ Hm,
    const unsigned short* __restrict__ W3,
    float* __restrict__ Out) {
  constexpr int K = 11008, N = 4096, NK = K / 64;
  __shared__ char ldsb[131072];

  const int tid = threadIdx.x;
  const int w = tid >> 6, l = tid & 63;

  const int bid = blockIdx.x;              // 256 = 8 * 32
  const int lt = (bid & 7) * 32 + (bid >> 3);
  const int mt = lt & 15, nt = lt >> 4;
  const int m0 = mt * 256, n0 = nt * 256;

  const int wr = w >> 2, wc = w & 3;

  const int lr = l >> 3;
  const int lc = ((l & 7) ^ lr) * 8;
  // A strip chunks: strip1 = rows {0-63,128-191} (dead after ph1),
  //                 strip2 = rows {64-127,192-255} (dead after ph3)
  const int astr = (w & 4) ? 8 : 0;
  const int cA10 = (w * 2 + 0) + astr, cA11 = (w * 2 + 1) + astr;
  const int cA20 = cA10 + 8, cA21 = cA11 + 8;
  const unsigned short* sA10 = Hm + (size_t)(m0 + cA10 * 8 + lr) * K + lc;
  const unsigned short* sA11 = Hm + (size_t)(m0 + cA11 * 8 + lr) * K + lc;
  const unsigned short* sA20 = Hm + (size_t)(m0 + cA20 * 8 + lr) * K + lc;
  const unsigned short* sA21 = Hm + (size_t)(m0 + cA21 * 8 + lr) * K + lc;
  const unsigned short* sB0  = W3 + (size_t)(n0 + (w * 4 + 0) * 8 + lr) * K + lc;
  const unsigned short* sB1_ = W3 + (size_t)(n0 + (w * 4 + 1) * 8 + lr) * K + lc;
  const unsigned short* sB2_ = W3 + (size_t)(n0 + (w * 4 + 2) * 8 + lr) * K + lc;
  const unsigned short* sB3_ = W3 + (size_t)(n0 + (w * 4 + 3) * 8 + lr) * K + lc;

#define ST_A_S1(t, BUF) { gload16(sA10 + (size_t)(t) * 64, ldsb + (BUF) * 32768 + cA10 * 1024); \
                          gload16(sA11 + (size_t)(t) * 64, ldsb + (BUF) * 32768 + cA11 * 1024); }
#define ST_A_S2(t, BUF) { gload16(sA20 + (size_t)(t) * 64, ldsb + (BUF) * 32768 + cA20 * 1024); \
                          gload16(sA21 + (size_t)(t) * 64, ldsb + (BUF) * 32768 + cA21 * 1024); }
#define ST_B_P1(t, BUF) { gload16(sB0  + (size_t)(t) * 64, ldsb + 65536 + (BUF) * 32768 + (w * 4 + 0) * 1024); \
                          gload16(sB1_ + (size_t)(t) * 64, ldsb + 65536 + (BUF) * 32768 + (w * 4 + 1) * 1024); }
#define ST_B_P2(t, BUF) { gload16(sB2_ + (size_t)(t) * 64, ldsb + 65536 + (BUF) * 32768 + (w * 4 + 2) * 1024); \
                          gload16(sB3_ + (size_t)(t) * 64, ldsb + 65536 + (BUF) * 32768 + (w * 4 + 3) * 1024); }

  const int slot0 = (((l >> 4)) ^ (l & 7)) << 4;
  const int slot1 = ((4 | (l >> 4)) ^ (l & 7)) << 4;
  const char* rdA = ldsb + (wr * 128 + (l & 15)) * 128;
  const char* rdB = ldsb + 65536 + (wc * 64 + (l & 15)) * 128;

  f32x4 acc[8][4] = {};
  bf16x8 a[4][2], b[4][2];

  // prologue: tile0 full + tile1 full; keep 8 in flight
  ST_A_S1(0, 0); ST_A_S2(0, 0); ST_B_P1(0, 0); ST_B_P2(0, 0);
  ST_A_S1(1, 1); ST_B_P1(1, 1); ST_A_S2(1, 1); ST_B_P2(1, 1);
  WAITV(8);
  barrier_nodrain();

#define OUT_TILE(T, BUF) { \
  const char* A_ = rdA + (BUF) * 32768; \
  const char* B_ = rdB + (BUF) * 32768; \
  /* ph1: read a[m0-3][ks0,ks1] + b[ks0]; MFMA m0-3 ks0 */ \
  _Pragma("unroll") for (int m = 0; m < 4; ++m) { \
    a[m][0] = *(const bf16x8*)(A_ + m * 2048 + slot0); \
    a[m][1] = *(const bf16x8*)(A_ + m * 2048 + slot1); } \
  _Pragma("unroll") for (int n = 0; n < 4; ++n) \
    b[n][0] = *(const bf16x8*)(B_ + n * 2048 + slot0); \
  barrier_nodrain(); LGKM0; \
  __builtin_amdgcn_s_setprio(1); \
  _Pragma("unroll") for (int m = 0; m < 4; ++m) \
    _Pragma("unroll") for (int n = 0; n < 4; ++n) \
      acc[m][n] = __builtin_amdgcn_mfma_f32_16x16x32_bf16(a[m][0], b[n][0], acc[m][n], 0, 0, 0); \
  __builtin_amdgcn_s_setprio(0); \
  barrier_nodrain(); \
  /* ph2: read b[ks1]; stage A(T+2) strip1; MFMA m0-3 ks1 */ \
  _Pragma("unroll") for (int n = 0; n < 4; ++n) \
    b[n][1] = *(const bf16x8*)(B_ + n * 2048 + slot1); \
  if ((T) + 2 < NK) ST_A_S1((T) + 2, BUF); \
  barrier_nodrain(); LGKM0; \
  __builtin_amdgcn_s_setprio(1); \
  _Pragma("unroll") for (int m = 0; m < 4; ++m) \
    _Pragma("unroll") for (int n = 0; n < 4; ++n) \
      acc[m][n] = __builtin_amdgcn_mfma_f32_16x16x32_bf16(a[m][1], b[n][1], acc[m][n], 0, 0, 0); \
  __builtin_amdgcn_s_setprio(0); \
  barrier_nodrain(); \
  /* ph3: read a[m4-7][ks0,ks1]; stage B(T+2) p1; MFMA m4-7 ks0 */ \
  _Pragma("unroll") for (int m = 0; m < 4; ++m) { \
    a[m][0] = *(const bf16x8*)(A_ + (m + 4) * 2048 + slot0); \
    a[m][1] = *(const bf16x8*)(A_ + (m + 4) * 2048 + slot1); } \
  if ((T) + 2 < NK) ST_B_P1((T) + 2, BUF); \
  barrier_nodrain(); LGKM0; \
  __builtin_amdgcn_s_setprio(1); \
  _Pragma("unroll") for (int m = 0; m < 4; ++m) \
    _Pragma("unroll") for (int n = 0; n < 4; ++n) \
      acc[m + 4][n] = __builtin_amdgcn_mfma_f32_16x16x32_bf16(a[m][0], b[n][0], acc[m + 4][n], 0, 0, 0); \
  __builtin_amdgcn_s_setprio(0); \
  barrier_nodrain(); \
  /* ph4: stage A(T+2) strip2 + B(T+2) p2; MFMA m4-7 ks1; boundary wait */ \
  if ((T) + 2 < NK) { ST_A_S2((T) + 2, BUF); ST_B_P2((T) + 2, BUF); } \
  barrier_nodrain(); LGKM0; \
  __builtin_amdgcn_s_setprio(1); \
  _Pragma("unroll") for (int m = 0; m < 4; ++m) \
    _Pragma("unroll") for (int n = 0; n < 4; ++n) \
      acc[m + 4][n] = __builtin_amdgcn_mfma_f32_16x16x32_bf16(a[m][1], b[n][1], acc[m + 4][n], 0, 0, 0); \
  __builtin_amdgcn_s_setprio(0); \
  if ((T) + 2 < NK) { WAITV(8); } else if ((T) + 1 < NK) { WAITV(0); } \
  barrier_nodrain(); }

  for (int tt = 0; tt < NK; tt += 2) {
    OUT_TILE(tt, 0);
    OUT_TILE(tt + 1, 1);
  }
#undef OUT_TILE
#undef ST_A_S1
#undef ST_A_S2
#undef ST_B_P1
#undef ST_B_P2

  const int er = (l >> 4) * 4, ec = l & 15;
#pragma unroll
  for (int m = 0; m < 8; ++m)
#pragma unroll
    for (int n = 0; n < 4; ++n) {
      const int row = m0 + wr * 128 + m * 16 + er;
      const int col = n0 + wc * 64 + n * 16 + ec;
      float* p = Out + (size_t)row * N + col;
#pragma unroll
      for (int j = 0; j < 4; ++j) p[(size_t)j * N] = acc[m][n][j];
    }
}

// ---------------------------------------------------------------------------
extern "C" void kernel_launch(void* const* d_in, const int* in_sizes, int n_in,
                              void* d_out, int out_size, void* d_ws, size_t ws_size,
                              hipStream_t stream) {
  const float* x  = (const float*)d_in[0];   // [2,2048,4096] -> [4096][4096]
  const float* w1 = (const float*)d_in[1];   // [11008,4096]
  const float* w2 = (const float*)d_in[2];   // [11008,4096]
  const float* w3 = (const float*)d_in[3];   // [4096,11008]
  float* out = (float*)d_out;

  char* ws = (char*)d_ws;
  unsigned short* xb  = (unsigned short*)(ws);                // 32 MiB
  unsigned short* w1b = (unsigned short*)(ws + 33554432);     // 86 MiB
  unsigned short* w2b = (unsigned short*)(ws + 123731968);    // 86 MiB
  unsigned short* hb  = (unsigned short*)(ws + 213909504);    // 86 MiB
  unsigned short* w3b = w1b;  // reuse after gemm1 (stream-ordered)

  const int NW = 11008 * 4096 / 4;
  k_f32_to_bf16<<<16384, 256, 0, stream>>>(x, xb, 4096 * 4096 / 4);
  k_dequant_nf4<<<NW / 256, 256, 0, stream>>>(w1, w1b, NW);
  k_dequant_nf4<<<NW / 256, 256, 0, stream>>>(w2, w2b, NW);

  // gate/up + SwiGLU -> h  (M=4096, N=11008, K=4096)
  k_gemm_dual_swiglu<<<1376, 512, 0, stream>>>(xb, w1b, w2b, hb);

  k_dequant_nf4<<<NW / 256, 256, 0, stream>>>(w3, w3b, NW);

  // out = h . w3^T  (M=4096, N=4096, K=11008)
  k_gemm_out<<<256, 512, 0, stream>>>(hb, w3b, out);
}

// Round 4
// 1271.357 us; speedup vs baseline: 1.1209x; 1.1209x over previous
//
#include <hip/hip_runtime.h>
#include <math.h>

typedef __attribute__((ext_vector_type(4))) float f32x4;
typedef __attribute__((ext_vector_type(8))) short bf16x8;

#define DI __device__ __forceinline__

DI unsigned short f32_to_bf16(float f) {
  unsigned int u = __float_as_uint(f);
  u += 0x7FFFu + ((u >> 16) & 1u);   // round-to-nearest-even
  return (unsigned short)(u >> 16);
}

static constexpr float kCode[16] = {
    -1.0f, -0.6961928009986877f, -0.5250730514526367f, -0.39491748809814453f,
    -0.28444138169288635f, -0.18477343022823334f, -0.09105003625154495f, 0.0f,
    0.07958029955625534f, 0.16093020141124725f, 0.24611230194568634f,
    0.33791524171829224f, 0.44070982933044434f, 0.5626170039176941f,
    0.7229568362236023f, 1.0f};

// ---------------------------------------------------------------------------
// NF4 quant-dequant (block=64): 16 lanes/block, float4/lane.
// ---------------------------------------------------------------------------
__global__ void __launch_bounds__(256) k_dequant_nf4(
    const float* __restrict__ in, unsigned short* __restrict__ out, int n4) {
  int i = blockIdx.x * 256 + threadIdx.x;
  if (i >= n4) return;
  f32x4 v = reinterpret_cast<const f32x4*>(in)[i];
  float am = fmaxf(fmaxf(fabsf(v.x), fabsf(v.y)), fmaxf(fabsf(v.z), fabsf(v.w)));
  am = fmaxf(am, __shfl_xor(am, 1));
  am = fmaxf(am, __shfl_xor(am, 2));
  am = fmaxf(am, __shfl_xor(am, 4));
  am = fmaxf(am, __shfl_xor(am, 8));
  float scale = (am == 0.0f) ? 1.0f : am;
  unsigned short o[4];
#pragma unroll
  for (int j = 0; j < 4; ++j) {
    float nv = ((const float*)&v)[j] / scale;
    int idx = 0;
#pragma unroll
    for (int b = 0; b < 15; ++b)
      idx += (nv > 0.5f * (kCode[b] + kCode[b + 1])) ? 1 : 0;
    o[j] = f32_to_bf16(kCode[idx] * am);
  }
  reinterpret_cast<ushort4*>(out)[i] = make_ushort4(o[0], o[1], o[2], o[3]);
}

__global__ void __launch_bounds__(256) k_f32_to_bf16(
    const float* __restrict__ in, unsigned short* __restrict__ out, int n4) {
  int i = blockIdx.x * 256 + threadIdx.x;
  if (i >= n4) return;
  f32x4 v = reinterpret_cast<const f32x4*>(in)[i];
  reinterpret_cast<ushort4*>(out)[i] =
      make_ushort4(f32_to_bf16(v.x), f32_to_bf16(v.y), f32_to_bf16(v.z), f32_to_bf16(v.w));
}

// ---------------------------------------------------------------------------
// GEMM helpers.
// LDS layout (BK=32, 64B rows): element (row,k) at byte
//   row*64 + (((k>>3) ^ ((row>>1)&3))<<4) + (k&7)*2
// Stage: global_load_lds writes linearly; lane l of a 1KB unit u covers
//   row 16u+(l>>2), k-chunk (l&3)^((l>>3)&3)  (verified element-wise).
// Read: frag byte = (rowbase+(l&15))*64 + ((l>>4)^((l>>1)&3))<<4  -> 2-way only.
// ---------------------------------------------------------------------------
DI void gload16(const void* g, void* l) {
  __builtin_amdgcn_global_load_lds(
      (const __attribute__((address_space(1))) void*)g,
      (__attribute__((address_space(3))) void*)l, 16, 0, 0);
}

DI void barrier_nodrain() {
  asm volatile("" ::: "memory");
  __builtin_amdgcn_s_barrier();
  asm volatile("" ::: "memory");
}

#define WAITV(N) asm volatile("s_waitcnt vmcnt(" #N ")" ::: "memory")

// ---------------------------------------------------------------------------
// Fused dual GEMM + SwiGLU. BM=256, BN=128, BK=32. 16 waves (1024 thr,
// 4 waves/SIMD): waves 0-7 = gate (B1), waves 8-15 = up (B2); pair p = w&7
// owns the same 64x64 tile at (wr=p>>1, wc=p&1). 4 LDS bufs x 32KB
// (A 16K | B1 8K | B2 8K), prefetch distance 3, vmcnt(4) boundary.
// Epilogue: f32 LDS exchange (m-split), both waves store half the rows.
// ---------------------------------------------------------------------------
__global__ void __launch_bounds__(1024, 4) k_gemm_dual_swiglu(
    const unsigned short* __restrict__ X,
    const unsigned short* __restrict__ W1,
    const unsigned short* __restrict__ W2,
    unsigned short* __restrict__ H) {
  constexpr int K = 4096, N = 11008, NK = K / 32;
  __shared__ char ldsb[131072];

  const int tid = threadIdx.x;
  const int w = tid >> 6, l = tid & 63;

  const int bid = blockIdx.x;               // 1376 = 8 * 172
  const int lt = (bid & 7) * 172 + (bid >> 3);
  const int mt = lt & 15, nt = lt >> 4;
  const int m0 = mt * 256, n0 = nt * 128;

  const int p = w & 7;
  const bool isGate = (w < 8);
  const int wr = p >> 1, wc = p & 1;

  // ---- staging assignment: 32 1KB-units, 2 per wave ----
  const int lrow = l >> 2;                              // 0..15
  const int kc8 = (((l & 3) ^ ((l >> 3) & 3)) << 3);    // 0,8,16,24 (elems)
  const unsigned short* gsrc0;
  const unsigned short* gsrc1;
  int ldst0;
  if (w < 8) {          // A units 2w, 2w+1 (rows 32w .. 32w+31)
    gsrc0 = X + (size_t)(m0 + 32 * w + lrow) * K + kc8;
    gsrc1 = X + (size_t)(m0 + 32 * w + 16 + lrow) * K + kc8;
    ldst0 = 2 * w * 1024;
  } else if (w < 12) {  // B1 units (rows n0 + 32(w-8) ..)
    gsrc0 = W1 + (size_t)(n0 + 32 * (w - 8) + lrow) * K + kc8;
    gsrc1 = W1 + (size_t)(n0 + 32 * (w - 8) + 16 + lrow) * K + kc8;
    ldst0 = 16384 + (w - 8) * 2048;
  } else {              // B2 units
    gsrc0 = W2 + (size_t)(n0 + 32 * (w - 12) + lrow) * K + kc8;
    gsrc1 = W2 + (size_t)(n0 + 32 * (w - 12) + 16 + lrow) * K + kc8;
    ldst0 = 24576 + (w - 12) * 2048;
  }

#define STG(t) { const int bo_ = (((t) & 3) << 15) + ldst0;          \
    gload16(gsrc0 + (size_t)(t) * 32, ldsb + bo_);                    \
    gload16(gsrc1 + (size_t)(t) * 32, ldsb + bo_ + 1024); }

  // ---- read bases ----
  const int roff = (((l >> 4) ^ ((l >> 1) & 3)) << 4);
  const char* rdA = ldsb + (wr * 64 + (l & 15)) * 64 + roff;
  const char* rdB = ldsb + 16384 + (isGate ? 0 : 8192) +
                    (wc * 64 + (l & 15)) * 64 + roff;

  f32x4 acc[4][4] = {};

  STG(0); STG(1); STG(2);
  WAITV(4);
  barrier_nodrain();

  for (int t = 0; t < NK; ++t) {
    const int bo = (t & 3) << 15;
    if (t + 3 < NK) STG(t + 3);
    bf16x8 a[4], b[4];
#pragma unroll
    for (int m = 0; m < 4; ++m) a[m] = *(const bf16x8*)(rdA + bo + m * 1024);
#pragma unroll
    for (int n = 0; n < 4; ++n) b[n] = *(const bf16x8*)(rdB + bo + n * 1024);
    __builtin_amdgcn_s_setprio(1);
#pragma unroll
    for (int m = 0; m < 4; ++m)
#pragma unroll
      for (int n = 0; n < 4; ++n)
        acc[m][n] = __builtin_amdgcn_mfma_f32_16x16x32_bf16(a[m], b[n], acc[m][n], 0, 0, 0);
    __builtin_amdgcn_s_setprio(0);
    if (t + 3 < NK)      { WAITV(4); barrier_nodrain(); }
    else if (t + 2 < NK) { WAITV(2); barrier_nodrain(); }
    else if (t + 1 < NK) { WAITV(0); barrier_nodrain(); }
  }
#undef STG

  // ---- epilogue: pairwise f32 exchange (m-split), balanced stores ----
  barrier_nodrain();  // staging LDS now dead for ALL waves
  char* xch = ldsb + p * 16384 + (isGate ? 0 : 8192);
  // gate writes its m=2,3 frags; up writes its m=0,1 frags
#pragma unroll
  for (int m2 = 0; m2 < 2; ++m2)
#pragma unroll
    for (int n = 0; n < 4; ++n) {
      const int m = isGate ? (m2 + 2) : m2;
      *(f32x4*)(xch + ((m2 * 4 + n) * 64 + l) * 16) = acc[m][n];
    }
  barrier_nodrain();
  const char* oxch = ldsb + p * 16384 + (isGate ? 8192 : 0);
  const int er = (l >> 4) * 4, ec = l & 15;
#pragma unroll
  for (int m2 = 0; m2 < 2; ++m2)
#pragma unroll
    for (int n = 0; n < 4; ++n) {
      const int m = isGate ? m2 : (m2 + 2);   // rows I store
      f32x4 other = *(const f32x4*)(oxch + ((m2 * 4 + n) * 64 + l) * 16);
#pragma unroll
      for (int j = 0; j < 4; ++j) {
        const float g_ = isGate ? acc[m][n][j] : other[j];
        const float u_ = isGate ? other[j] : acc[m][n][j];
        const float s = g_ / (1.0f + expf(-g_));
        const int row = m0 + wr * 64 + m * 16 + er + j;
        const int col = n0 + wc * 64 + n * 16 + ec;
        H[(size_t)row * N + col] = f32_to_bf16(s * u_);
      }
    }
}

// ---------------------------------------------------------------------------
// Output GEMM. BM=BN=256, BK=32, 16 waves (4M x 4N), per-wave 64x64.
// 4 LDS bufs x 32KB (A 16K | B 16K), prefetch 3, vmcnt(4).
// H:[4096][11008] bf16, W3:[4096][11008] bf16 -> Out:[4096][4096] f32
// ---------------------------------------------------------------------------
__global__ void __launch_bounds__(1024, 4) k_gemm_out(
    const unsigned short* __restrict__ Hm,
    const unsigned short* __restrict__ W3,
    float* __restrict__ Out) {
  constexpr int K = 11008, N = 4096, NK = K / 32;
  __shared__ char ldsb[131072];

  const int tid = threadIdx.x;
  const int w = tid >> 6, l = tid & 63;

  const int bid = blockIdx.x;              // 256 = 8 * 32
  const int lt = (bid & 7) * 32 + (bid >> 3);
  const int mt = lt & 15, nt = lt >> 4;
  const int m0 = mt * 256, n0 = nt * 256;

  const int wr = w >> 2, wc = w & 3;

  const int lrow = l >> 2;
  const int kc8 = (((l & 3) ^ ((l >> 3) & 3)) << 3);
  const unsigned short* gsrc0;
  const unsigned short* gsrc1;
  int ldst0;
  if (w < 8) {          // A units
    gsrc0 = Hm + (size_t)(m0 + 32 * w + lrow) * K + kc8;
    gsrc1 = Hm + (size_t)(m0 + 32 * w + 16 + lrow) * K + kc8;
    ldst0 = 2 * w * 1024;
  } else {              // B units
    gsrc0 = W3 + (size_t)(n0 + 32 * (w - 8) + lrow) * K + kc8;
    gsrc1 = W3 + (size_t)(n0 + 32 * (w - 8) + 16 + lrow) * K + kc8;
    ldst0 = 16384 + (w - 8) * 2048;
  }

#define STG(t) { const int bo_ = (((t) & 3) << 15) + ldst0;          \
    gload16(gsrc0 + (size_t)(t) * 32, ldsb + bo_);                    \
    gload16(gsrc1 + (size_t)(t) * 32, ldsb + bo_ + 1024); }

  const int roff = (((l >> 4) ^ ((l >> 1) & 3)) << 4);
  const char* rdA = ldsb + (wr * 64 + (l & 15)) * 64 + roff;
  const char* rdB = ldsb + 16384 + (wc * 64 + (l & 15)) * 64 + roff;

  f32x4 acc[4][4] = {};

  STG(0); STG(1); STG(2);
  WAITV(4);
  barrier_nodrain();

  for (int t = 0; t < NK; ++t) {
    const int bo = (t & 3) << 15;
    if (t + 3 < NK) STG(t + 3);
    bf16x8 a[4], b[4];
#pragma unroll
    for (int m = 0; m < 4; ++m) a[m] = *(const bf16x8*)(rdA + bo + m * 1024);
#pragma unroll
    for (int n = 0; n < 4; ++n) b[n] = *(const bf16x8*)(rdB + bo + n * 1024);
    __builtin_amdgcn_s_setprio(1);
#pragma unroll
    for (int m = 0; m < 4; ++m)
#pragma unroll
      for (int n = 0; n < 4; ++n)
        acc[m][n] = __builtin_amdgcn_mfma_f32_16x16x32_bf16(a[m], b[n], acc[m][n], 0, 0, 0);
    __builtin_amdgcn_s_setprio(0);
    if (t + 3 < NK)      { WAITV(4); barrier_nodrain(); }
    else if (t + 2 < NK) { WAITV(2); barrier_nodrain(); }
    else if (t + 1 < NK) { WAITV(0); barrier_nodrain(); }
  }
#undef STG

  const int er = (l >> 4) * 4, ec = l & 15;
#pragma unroll
  for (int m = 0; m < 4; ++m)
#pragma unroll
    for (int n = 0; n < 4; ++n) {
      const int row = m0 + wr * 64 + m * 16 + er;
      const int col = n0 + wc * 64 + n * 16 + ec;
      float* ptr = Out + (size_t)row * N + col;
#pragma unroll
      for (int j = 0; j < 4; ++j) ptr[(size_t)j * N] = acc[m][n][j];
    }
}

// ---------------------------------------------------------------------------
extern "C" void kernel_launch(void* const* d_in, const int* in_sizes, int n_in,
                              void* d_out, int out_size, void* d_ws, size_t ws_size,
                              hipStream_t stream) {
  const float* x  = (const float*)d_in[0];   // [2,2048,4096] -> [4096][4096]
  const float* w1 = (const float*)d_in[1];   // [11008,4096]
  const float* w2 = (const float*)d_in[2];   // [11008,4096]
  const float* w3 = (const float*)d_in[3];   // [4096,11008]
  float* out = (float*)d_out;

  char* ws = (char*)d_ws;
  unsigned short* xb  = (unsigned short*)(ws);                // 32 MiB
  unsigned short* w1b = (unsigned short*)(ws + 33554432);     // 86 MiB
  unsigned short* w2b = (unsigned short*)(ws + 123731968);    // 86 MiB
  unsigned short* hb  = (unsigned short*)(ws + 213909504);    // 86 MiB
  unsigned short* w3b = w1b;  // reuse after gemm1 (stream-ordered)

  const int NW = 11008 * 4096 / 4;
  k_f32_to_bf16<<<16384, 256, 0, stream>>>(x, xb, 4096 * 4096 / 4);
  k_dequant_nf4<<<NW / 256, 256, 0, stream>>>(w1, w1b, NW);
  k_dequant_nf4<<<NW / 256, 256, 0, stream>>>(w2, w2b, NW);

  // gate/up + SwiGLU -> h  (M=4096, N=11008, K=4096)
  k_gemm_dual_swiglu<<<1376, 1024, 0, stream>>>(xb, w1b, w2b, hb);

  k_dequant_nf4<<<NW / 256, 256, 0, stream>>>(w3, w3b, NW);

  // out = h . w3^T  (M=4096, N=4096, K=11008)
  k_gemm_out<<<256, 1024, 0, stream>>>(hb, w3b, out);
}